// Round 6
// baseline (580.398 us; speedup 1.0000x reference)
//
#include <hip/hip_runtime.h>

#define N0_ 1000000
#define N1_ 200000
#define N2_ 20000
#define N3_ 2048
#define E0_ 2000000
#define E1_ 200000
#define E2_ 20480
#define IN_ 128
#define HID_ 256
#define OUT_ 47

#define NTOT_ (N1_ + N2_ + N3_)          // 222048
#define ETOT_ (E0_ + E1_ + E2_)          // 2220480

typedef unsigned short u16;
typedef unsigned int u32;
typedef __attribute__((ext_vector_type(8))) short b16x8;
typedef __attribute__((ext_vector_type(4))) float f32x4;
typedef __attribute__((ext_vector_type(4))) u16 u16x4;
typedef __attribute__((ext_vector_type(8))) u16 u16x8;

__device__ __forceinline__ u16 f2b(float f) {  // RNE fp32->bf16
  u32 u = __builtin_bit_cast(u32, f);
  return (u16)((u + 0x7FFFu + ((u >> 16) & 1u)) >> 16);
}
__device__ __forceinline__ float b2f(u16 b) {
  return __builtin_bit_cast(float, (u32)b << 16);
}

// ---------------- workspace layout (4-byte words) ----------------
static constexpr size_t OFF_CNT  = 0;           // NTOT (hist counts)
static constexpr size_t OFF_CUR  = 222048;      // NTOT (fill cursors) - adjacent: one memset
static constexpr size_t OFF_RPTR = 444096;      // NTOT+1 (pad to 222080)
static constexpr size_t OFF_BSUM = 666176;      // 128
static constexpr size_t OFF_EIDS = 666304;      // ETOT
static constexpr size_t OFF_BT0  = 2886784;     // 32768  (256n x 256k bf16)
static constexpr size_t OFF_BT1  = 2919552;     // 65536  (256n x 512k bf16)
static constexpr size_t OFF_H1   = 2985088;     // 25600000 (200000x256 bf16)
static constexpr size_t OFF_HN1  = 28585088;    // 2560000  (20000x256 bf16)
static constexpr size_t OFF_H2   = 31145088;    // 2560000
// end: 33,705,088 words = 135 MB

// ---------------- combined prep: 3-layer histogram + weight packs ----------------
__global__ __launch_bounds__(256) void prep(
    const int* __restrict__ dst0, const int* __restrict__ dst1,
    const int* __restrict__ dst2,
    const float* __restrict__ Ws0, const float* __restrict__ Wn0,
    const float* __restrict__ Ws1, const float* __restrict__ Wn1,
    int* __restrict__ cnt, u16* __restrict__ Bt0, u16* __restrict__ Bt1) {
  int t = blockIdx.x * 256 + threadIdx.x;
  if (t < E0_) { atomicAdd(&cnt[dst0[t]], 1); return; }
  t -= E0_;
  if (t < E1_) { atomicAdd(&cnt[N1_ + dst1[t]], 1); return; }
  t -= E1_;
  if (t < E2_) { atomicAdd(&cnt[N1_ + N2_ + dst2[t]], 1); return; }
  t -= E2_;
  if (t < 256 * 256) {  // Bt0: [n][k], KT=256
    int n = t & 255, k = t >> 8;
    float v = (k < IN_) ? Ws0[(size_t)k * 256 + n] : Wn0[(size_t)(k - IN_) * 256 + n];
    Bt0[(size_t)n * 256 + k] = f2b(v);
    return;
  }
  t -= 256 * 256;
  if (t < 256 * 512) {  // Bt1: [n][k], KT=512
    int n = t & 255, k = t >> 8;
    float v = (k < HID_) ? Ws1[(size_t)k * 256 + n] : Wn1[(size_t)(k - HID_) * 256 + n];
    Bt1[(size_t)n * 512 + k] = f2b(v);
  }
}

// ---------------- scan over NTOT counts ----------------
__global__ __launch_bounds__(256) void scan_local(const int* __restrict__ in,
                                                  int* __restrict__ out,
                                                  int* __restrict__ bsum, int n) {
  __shared__ int s[256];
  const int b = blockIdx.x, t = threadIdx.x;
  const int base = b * 2048 + t * 8;
  int v[8];
  int sum = 0;
#pragma unroll
  for (int i = 0; i < 8; i++) {
    int idx = base + i;
    int x = (idx < n) ? in[idx] : 0;
    v[i] = sum;
    sum += x;
  }
  s[t] = sum;
  __syncthreads();
  for (int off = 1; off < 256; off <<= 1) {
    int x = 0;
    if (t >= off) x = s[t - off];
    __syncthreads();
    if (t >= off) s[t] += x;
    __syncthreads();
  }
  const int texcl = s[t] - sum;
#pragma unroll
  for (int i = 0; i < 8; i++) {
    int idx = base + i;
    if (idx < n) out[idx] = texcl + v[i];
  }
  if (t == 255) bsum[b] = s[255];
}

__global__ __launch_bounds__(256) void scan_add(int* __restrict__ rptr,
                                                const int* __restrict__ bsum,
                                                int n, int E) {
  const int b = blockIdx.x, t = threadIdx.x;
  int add = 0;
  for (int i = 0; i < b; i++) add += bsum[i];
  const int base = b * 2048 + t * 8;
#pragma unroll
  for (int i = 0; i < 8; i++) {
    int idx = base + i;
    if (idx < n) rptr[idx] += add;
  }
  if (b == 0 && t == 0) rptr[n] = E;
}

// ---------------- combined fill: block-diagonal CSR ----------------
__global__ __launch_bounds__(256) void csr_fill_all(
    const int* __restrict__ src0, const int* __restrict__ dst0,
    const int* __restrict__ src1, const int* __restrict__ dst1,
    const int* __restrict__ src2, const int* __restrict__ dst2,
    const int* __restrict__ rptr, int* __restrict__ cursor,
    int* __restrict__ eids) {
  int e = blockIdx.x * 256 + threadIdx.x;
  int s, b;
  if (e < E0_) { s = src0[e]; b = dst0[e]; }
  else if (e < E0_ + E1_) { s = src1[e - E0_]; b = N1_ + dst1[e - E0_]; }
  else if (e < ETOT_) { s = src2[e - E0_ - E1_]; b = N1_ + N2_ + dst2[e - E0_ - E1_]; }
  else return;
  int pos = rptr[b] + atomicAdd(&cursor[b], 1);
  eids[pos] = s;
}

// ---------------- fused layer 0: gather+mean -> LDS -> MFMA GEMM ----------------
// BM=128, BN=256, 512 threads (8 waves, 2m x 4n quadrants). LDS 80KB -> 2 blocks/CU.
__global__ __launch_bounds__(512, 4) void fused_sage0(
    const float* __restrict__ x, const int* __restrict__ eids,
    const int* __restrict__ rptr, const u16* __restrict__ Bt,
    const float* __restrict__ bias, u16* __restrict__ outp, int M) {
  __shared__ u16 Bs[256 * 64];   // 32 KB [n][k] swizzled
  __shared__ u16 As[128 * 64];   // 16 KB [m][k] swizzled
  __shared__ u16 HN[128 * 128];  // 32 KB [m][k] swizzled (row stride 256B)
  const int tid = threadIdx.x;
  const int lane = tid & 63;
  const int wv = tid >> 6;
  const int m0 = blockIdx.x * 128;

  // ---- phase 1: gather + mean, 16 rows per wave ----
  {
    const int half = lane >> 5;
    const int colf = (lane & 31) * 4;   // fp32 col
    for (int r = 0; r < 16; r++) {
      const int rl = wv * 16 + r;
      int rowg = m0 + rl; if (rowg >= M) rowg = M - 1;
      const int beg = rptr[rowg], end = rptr[rowg + 1];
      float a0 = 0.f, a1 = 0.f, a2 = 0.f, a3 = 0.f;
      for (int i = beg; i < end; i += 16) {
        int ids[8];
#pragma unroll
        for (int j = 0; j < 8; j++) {
          int idx = i + 2 * j + half;
          idx = idx < end ? idx : end - 1;
          ids[j] = eids[idx];
        }
        float4 v[8];
#pragma unroll
        for (int j = 0; j < 8; j++)
          v[j] = *reinterpret_cast<const float4*>(&x[(size_t)ids[j] * IN_ + colf]);
#pragma unroll
        for (int j = 0; j < 8; j++) {
          if (i + 2 * j + half < end) {
            a0 += v[j].x; a1 += v[j].y; a2 += v[j].z; a3 += v[j].w;
          }
        }
      }
      a0 += __shfl_xor(a0, 32, 64);
      a1 += __shfl_xor(a1, 32, 64);
      a2 += __shfl_xor(a2, 32, 64);
      a3 += __shfl_xor(a3, 32, 64);
      if (half == 0) {
        float inv = 1.0f / fmaxf((float)(end - beg), 1.0f);
        u32 p0 = (u32)f2b(a0 * inv) | ((u32)f2b(a1 * inv) << 16);
        u32 p1 = (u32)f2b(a2 * inv) | ((u32)f2b(a3 * inv) << 16);
        int byt = (rl * 256 + colf * 2) ^ ((rl & 7) << 4);
        u32* dp = reinterpret_cast<u32*>(reinterpret_cast<char*>(HN) + byt);
        dp[0] = p0; dp[1] = p1;
      }
    }
  }
  __syncthreads();

  // ---- phase 2: MFMA GEMM, A = [x (staged) | HN (in place)] ----
  const int wm = wv >> 2;
  const int wn = wv & 3;
  f32x4 acc[4][4];
#pragma unroll
  for (int m = 0; m < 4; m++)
#pragma unroll
    for (int n = 0; n < 4; n++) acc[m][n] = f32x4{0.f, 0.f, 0.f, 0.f};

#pragma unroll
  for (int kt = 0; kt < 256; kt += 64) {
    if (kt < 128) {
      // stage As from x (fp32 -> bf16)
#pragma unroll
      for (int i = 0; i < 4; i++) {
        int e = tid + i * 512;           // 0..2047 float4s
        int row = e >> 4;
        int c = (e & 15) * 4;
        int rowg = m0 + row; if (rowg >= M) rowg = M - 1;
        float4 v = *reinterpret_cast<const float4*>(&x[(size_t)rowg * IN_ + kt + c]);
        u32 p0 = (u32)f2b(v.x) | ((u32)f2b(v.y) << 16);
        u32 p1 = (u32)f2b(v.z) | ((u32)f2b(v.w) << 16);
        int byt = ((row * 64 + c) * 2) ^ ((row & 7) << 4);
        u32* dp = reinterpret_cast<u32*>(reinterpret_cast<char*>(As) + byt);
        dp[0] = p0; dp[1] = p1;
      }
    }
    // stage Bs
#pragma unroll
    for (int i = 0; i < 4; i++) {
      int e = tid + i * 512;             // 0..2047 u16x8s
      int n = e >> 3;
      int ch = e & 7;
      u16x8 v = *reinterpret_cast<const u16x8*>(&Bt[(size_t)n * 256 + kt + ch * 8]);
      int byt = ((n * 64 + ch * 8) * 2) ^ ((n & 7) << 4);
      *reinterpret_cast<u16x8*>(reinterpret_cast<char*>(Bs) + byt) = v;
    }
    __syncthreads();
#pragma unroll
    for (int kk = 0; kk < 64; kk += 32) {
      const int ksl = kk + (lane >> 4) * 8;
      b16x8 a[4], b[4];
#pragma unroll
      for (int m = 0; m < 4; m++) {
        int row = wm * 64 + m * 16 + (lane & 15);
        if (kt < 128) {
          int byt = (row * 128 + ksl * 2) ^ ((row & 7) << 4);
          a[m] = *reinterpret_cast<const b16x8*>(reinterpret_cast<const char*>(As) + byt);
        } else {
          int byt = (row * 256 + (kt - 128 + ksl) * 2) ^ ((row & 7) << 4);
          a[m] = *reinterpret_cast<const b16x8*>(reinterpret_cast<const char*>(HN) + byt);
        }
      }
#pragma unroll
      for (int n = 0; n < 4; n++) {
        int row = wn * 64 + n * 16 + (lane & 15);
        int byt = (row * 128 + ksl * 2) ^ ((row & 7) << 4);
        b[n] = *reinterpret_cast<const b16x8*>(reinterpret_cast<const char*>(Bs) + byt);
      }
#pragma unroll
      for (int m = 0; m < 4; m++)
#pragma unroll
        for (int n = 0; n < 4; n++)
          acc[m][n] = __builtin_amdgcn_mfma_f32_16x16x32_bf16(a[m], b[n], acc[m][n], 0, 0, 0);
    }
    __syncthreads();
  }
  // ---- epilogue ----
  float bv[4];
#pragma unroll
  for (int n = 0; n < 4; n++) bv[n] = bias[wn * 64 + n * 16 + (lane & 15)];
#pragma unroll
  for (int m = 0; m < 4; m++) {
    int rowb = m0 + wm * 64 + m * 16 + ((lane >> 4) << 2);
#pragma unroll
    for (int r = 0; r < 4; r++) {
      int row = rowb + r;
      if (row < M) {
#pragma unroll
        for (int n = 0; n < 4; n++) {
          float v = acc[m][n][r] + bv[n];
          v = fmaxf(v, 0.0f);
          outp[(size_t)row * 256 + wn * 64 + n * 16 + (lane & 15)] = f2b(v);
        }
      }
    }
  }
}

// ---------------- layer-1 aggregate (bf16 source, F=256) ----------------
__global__ __launch_bounds__(256) void agg1(const u16* __restrict__ h,
                                            const int* __restrict__ eids,
                                            const int* __restrict__ rptr,
                                            u16* __restrict__ out, int M) {
  int wid = (blockIdx.x * 256 + threadIdx.x) >> 6;
  int lane = threadIdx.x & 63;
  if (wid >= M) return;
  const int beg = rptr[wid], end = rptr[wid + 1];
  const int half = lane >> 5;
  const int col = (lane & 31) * 8;
  float a[8];
#pragma unroll
  for (int j = 0; j < 8; j++) a[j] = 0.f;
  for (int i = beg; i < end; i += 16) {
    int ids[8];
#pragma unroll
    for (int j = 0; j < 8; j++) {
      int idx = i + 2 * j + half;
      idx = idx < end ? idx : end - 1;
      ids[j] = eids[idx];
    }
    u16x8 v[8];
#pragma unroll
    for (int j = 0; j < 8; j++)
      v[j] = *reinterpret_cast<const u16x8*>(&h[(size_t)ids[j] * HID_ + col]);
#pragma unroll
    for (int j = 0; j < 8; j++) {
      if (i + 2 * j + half < end) {
#pragma unroll
        for (int c = 0; c < 8; c++) a[c] += b2f(v[j][c]);
      }
    }
  }
#pragma unroll
  for (int c = 0; c < 8; c++) a[c] += __shfl_xor(a[c], 32, 64);
  if (half == 0) {
    float inv = 1.0f / fmaxf((float)(end - beg), 1.0f);
    u16x8 o;
#pragma unroll
    for (int c = 0; c < 8; c++) o[c] = f2b(a[c] * inv);
    *reinterpret_cast<u16x8*>(&out[(size_t)wid * HID_ + col]) = o;
  }
}

// ---------------- layer-1 MFMA GEMM (unfused) ----------------
template <int KSELF>
__global__ __launch_bounds__(512) void sage_gemm_mfma(
    const u16* __restrict__ A0, const u16* __restrict__ A1,
    const u16* __restrict__ Bt, const float* __restrict__ bias,
    u16* __restrict__ outp, int M) {
  constexpr int KTOT = 2 * KSELF;
  __shared__ u16 As[128 * 64];
  __shared__ u16 Bs[256 * 64];
  const int tid = threadIdx.x;
  const int lane = tid & 63;
  const int w = tid >> 6;
  const int wm = w >> 2;
  const int wn = w & 3;
  const int m0 = blockIdx.x * 128;

  f32x4 acc[4][4];
#pragma unroll
  for (int m = 0; m < 4; m++)
#pragma unroll
    for (int n = 0; n < 4; n++) acc[m][n] = f32x4{0.f, 0.f, 0.f, 0.f};

  for (int kt = 0; kt < KTOT; kt += 64) {
    const u16* src; int ksrc;
    if (kt < KSELF) { src = A0; ksrc = kt; }
    else            { src = A1; ksrc = kt - KSELF; }
#pragma unroll
    for (int i = 0; i < 2; i++) {
      int e = tid + i * 512;
      int row = e >> 3;
      int ch = e & 7;
      int rowg = m0 + row; if (rowg >= M) rowg = M - 1;
      u16x8 v = *reinterpret_cast<const u16x8*>(&src[(size_t)rowg * KSELF + ksrc + ch * 8]);
      int byt = ((row * 64 + ch * 8) * 2) ^ ((row & 7) << 4);
      *reinterpret_cast<u16x8*>(reinterpret_cast<char*>(As) + byt) = v;
    }
#pragma unroll
    for (int i = 0; i < 4; i++) {
      int e = tid + i * 512;
      int n = e >> 3;
      int ch = e & 7;
      u16x8 v = *reinterpret_cast<const u16x8*>(&Bt[(size_t)n * KTOT + kt + ch * 8]);
      int byt = ((n * 64 + ch * 8) * 2) ^ ((n & 7) << 4);
      *reinterpret_cast<u16x8*>(reinterpret_cast<char*>(Bs) + byt) = v;
    }
    __syncthreads();
#pragma unroll
    for (int kk = 0; kk < 64; kk += 32) {
      const int kb = (kk + (lane >> 4) * 8) * 2;
      b16x8 a[4], b[4];
#pragma unroll
      for (int m = 0; m < 4; m++) {
        int row = wm * 64 + m * 16 + (lane & 15);
        int byt = (row * 128 + kb) ^ ((row & 7) << 4);
        a[m] = *reinterpret_cast<const b16x8*>(reinterpret_cast<const char*>(As) + byt);
      }
#pragma unroll
      for (int n = 0; n < 4; n++) {
        int row = wn * 64 + n * 16 + (lane & 15);
        int byt = (row * 128 + kb) ^ ((row & 7) << 4);
        b[n] = *reinterpret_cast<const b16x8*>(reinterpret_cast<const char*>(Bs) + byt);
      }
#pragma unroll
      for (int m = 0; m < 4; m++)
#pragma unroll
        for (int n = 0; n < 4; n++)
          acc[m][n] = __builtin_amdgcn_mfma_f32_16x16x32_bf16(a[m], b[n], acc[m][n], 0, 0, 0);
    }
    __syncthreads();
  }
  float bv[4];
#pragma unroll
  for (int n = 0; n < 4; n++) bv[n] = bias[wn * 64 + n * 16 + (lane & 15)];
#pragma unroll
  for (int m = 0; m < 4; m++) {
    int rowb = m0 + wm * 64 + m * 16 + ((lane >> 4) << 2);
#pragma unroll
    for (int r = 0; r < 4; r++) {
      int row = rowb + r;
      if (row < M) {
#pragma unroll
        for (int n = 0; n < 4; n++) {
          float v = acc[m][n][r] + bv[n];
          v = fmaxf(v, 0.0f);
          outp[(size_t)row * 256 + wn * 64 + n * 16 + (lane & 15)] = f2b(v);
        }
      }
    }
  }
}

// ---------------- fused final layer: gather + GEMM (M=2048, K=512, N=47) ----------------
__global__ __launch_bounds__(64) void fused_out(
    const u16* __restrict__ h, const int* __restrict__ eids,
    const int* __restrict__ rptr, const float* __restrict__ Ws,
    const float* __restrict__ Wn, const float* __restrict__ bias,
    float* __restrict__ out) {
  __shared__ float As[512];
  const int row = blockIdx.x;
  const int t = threadIdx.x;
  u16x4 a = *reinterpret_cast<const u16x4*>(&h[(size_t)row * 256 + t * 4]);
#pragma unroll
  for (int j = 0; j < 4; j++) As[t * 4 + j] = b2f(a[j]);
  // gather h_neigh for this row, lane t owns cols t*4..t*4+3
  const int beg = rptr[row], end = rptr[row + 1];
  float s0 = 0.f, s1 = 0.f, s2 = 0.f, s3 = 0.f;
  for (int i = beg; i < end; i += 4) {
    int i1 = (i + 1 < end) ? i + 1 : i;
    int i2 = (i + 2 < end) ? i + 2 : i;
    int i3 = (i + 3 < end) ? i + 3 : i;
    int e0 = eids[i], e1 = eids[i1], e2 = eids[i2], e3 = eids[i3];
    u16x4 v0 = *reinterpret_cast<const u16x4*>(&h[(size_t)e0 * 256 + t * 4]);
    u16x4 v1 = *reinterpret_cast<const u16x4*>(&h[(size_t)e1 * 256 + t * 4]);
    u16x4 v2 = *reinterpret_cast<const u16x4*>(&h[(size_t)e2 * 256 + t * 4]);
    u16x4 v3 = *reinterpret_cast<const u16x4*>(&h[(size_t)e3 * 256 + t * 4]);
    s0 += b2f(v0[0]); s1 += b2f(v0[1]); s2 += b2f(v0[2]); s3 += b2f(v0[3]);
    if (i + 1 < end) { s0 += b2f(v1[0]); s1 += b2f(v1[1]); s2 += b2f(v1[2]); s3 += b2f(v1[3]); }
    if (i + 2 < end) { s0 += b2f(v2[0]); s1 += b2f(v2[1]); s2 += b2f(v2[2]); s3 += b2f(v2[3]); }
    if (i + 3 < end) { s0 += b2f(v3[0]); s1 += b2f(v3[1]); s2 += b2f(v3[2]); s3 += b2f(v3[3]); }
  }
  float inv = 1.0f / fmaxf((float)(end - beg), 1.0f);
  As[256 + t * 4 + 0] = s0 * inv;
  As[256 + t * 4 + 1] = s1 * inv;
  As[256 + t * 4 + 2] = s2 * inv;
  As[256 + t * 4 + 3] = s3 * inv;
  __syncthreads();
  if (t < OUT_) {
    float s = bias[t];
#pragma unroll 8
    for (int k = 0; k < 256; k++) s = fmaf(As[k], Ws[k * 47 + t], s);
#pragma unroll 8
    for (int k = 0; k < 256; k++) s = fmaf(As[256 + k], Wn[k * 47 + t], s);
    out[(size_t)row * 47 + t] = s;
  }
}

// ---------------- host driver ----------------
extern "C" void kernel_launch(void* const* d_in, const int* in_sizes, int n_in,
                              void* d_out, int out_size, void* d_ws, size_t ws_size,
                              hipStream_t stream) {
  const float* x      = (const float*)d_in[0];
  const int*   src0   = (const int*)d_in[1];
  const int*   dst0   = (const int*)d_in[2];
  const int*   src1   = (const int*)d_in[3];
  const int*   dst1   = (const int*)d_in[4];
  const int*   src2   = (const int*)d_in[5];
  const int*   dst2   = (const int*)d_in[6];
  const float* Wself0 = (const float*)d_in[7];
  const float* Wneigh0= (const float*)d_in[8];
  const float* b0     = (const float*)d_in[9];
  const float* Wself1 = (const float*)d_in[10];
  const float* Wneigh1= (const float*)d_in[11];
  const float* b1     = (const float*)d_in[12];
  const float* Wself2 = (const float*)d_in[13];
  const float* Wneigh2= (const float*)d_in[14];
  const float* b2     = (const float*)d_in[15];

  int* wsi   = (int*)d_ws;
  int* cnt   = wsi + OFF_CNT;
  int* cursor= wsi + OFF_CUR;
  int* rptr  = wsi + OFF_RPTR;
  int* bsum  = wsi + OFF_BSUM;
  int* eids  = wsi + OFF_EIDS;
  u16* Bt0   = (u16*)(wsi + OFF_BT0);
  u16* Bt1   = (u16*)(wsi + OFF_BT1);
  u16* H1    = (u16*)(wsi + OFF_H1);
  u16* HN1   = (u16*)(wsi + OFF_HN1);
  u16* H2    = (u16*)(wsi + OFF_H2);
  float* out = (float*)d_out;

  // one memset for counts + cursors
  hipMemsetAsync(cnt, 0, (size_t)(2 * NTOT_) * 4, stream);

  // combined hist (3 layers) + weight packs
  {
    int total = ETOT_ + 256 * 256 + 256 * 512;
    prep<<<(total + 255) / 256, 256, 0, stream>>>(
        dst0, dst1, dst2, Wself0, Wneigh0, Wself1, Wneigh1, cnt, Bt0, Bt1);
  }
  // combined scan + fill (block-diagonal CSR over all 3 layers)
  {
    const int nb = (NTOT_ + 2047) / 2048;  // 109
    scan_local<<<nb, 256, 0, stream>>>(cnt, rptr, bsum, NTOT_);
    scan_add<<<nb, 256, 0, stream>>>(rptr, bsum, NTOT_, ETOT_);
    csr_fill_all<<<(ETOT_ + 255) / 256, 256, 0, stream>>>(
        src0, dst0, src1, dst1, src2, dst2, rptr, cursor, eids);
  }

  // ---- layer 0 (fused gather + GEMM) ----
  fused_sage0<<<(N1_ + 127) / 128, 512, 0, stream>>>(x, eids, rptr, Bt0, b0, H1, N1_);

  // ---- layer 1 ----
  agg1<<<(N2_ + 3) / 4, 256, 0, stream>>>(H1, eids, rptr + N1_, HN1, N2_);
  sage_gemm_mfma<HID_><<<(N2_ + 127) / 128, 512, 0, stream>>>(H1, HN1, Bt1, b1, H2, N2_);

  // ---- layer 2 (fused gather + output GEMM) ----
  fused_out<<<N3_, 64, 0, stream>>>(H2, eids, rptr + N1_ + N2_, Wself2, Wneigh2, b2, out);
}

// Round 7
// 550.365 us; speedup vs baseline: 1.0546x; 1.0546x over previous
//
#include <hip/hip_runtime.h>

#define N0_ 1000000
#define N1_ 200000
#define N2_ 20000
#define N3_ 2048
#define E0_ 2000000
#define E1_ 200000
#define E2_ 20480
#define IN_ 128
#define HID_ 256
#define OUT_ 47

#define NTOT_ (N1_ + N2_ + N3_)          // 222048
#define ETOT_ (E0_ + E1_ + E2_)          // 2220480

typedef unsigned short u16;
typedef unsigned int u32;
typedef __attribute__((ext_vector_type(8))) short b16x8;
typedef __attribute__((ext_vector_type(4))) float f32x4;
typedef __attribute__((ext_vector_type(4))) u16 u16x4;
typedef __attribute__((ext_vector_type(8))) u16 u16x8;

__device__ __forceinline__ u16 f2b(float f) {  // RNE fp32->bf16
  u32 u = __builtin_bit_cast(u32, f);
  return (u16)((u + 0x7FFFu + ((u >> 16) & 1u)) >> 16);
}
__device__ __forceinline__ float b2f(u16 b) {
  return __builtin_bit_cast(float, (u32)b << 16);
}

// ---------------- workspace layout (4-byte words) ----------------
static constexpr size_t OFF_CNT  = 0;           // NTOT (hist counts)
static constexpr size_t OFF_CUR  = 222048;      // NTOT (fill cursors) - adjacent: one memset
static constexpr size_t OFF_RPTR = 444096;      // NTOT+1
static constexpr size_t OFF_BSUM = 666176;      // 128
static constexpr size_t OFF_EIDS = 666304;      // ETOT
static constexpr size_t OFF_BT0  = 2886784;     // 32768  (256n x 256k bf16)
static constexpr size_t OFF_BT1  = 2919552;     // 65536  (256n x 512k bf16)
static constexpr size_t OFF_HN0  = 2985088;     // 12800000 (200000x128 bf16)
static constexpr size_t OFF_H1   = 15785088;    // 25600000 (200000x256 bf16)
static constexpr size_t OFF_HN1  = 41385088;    // 2560000  (20000x256 bf16)
static constexpr size_t OFF_H2   = 43945088;    // 2560000
// end: 46,505,088 words = 186 MB

// ---------------- combined prep: 3-layer histogram + weight packs ----------------
__global__ __launch_bounds__(256) void prep(
    const int* __restrict__ dst0, const int* __restrict__ dst1,
    const int* __restrict__ dst2,
    const float* __restrict__ Ws0, const float* __restrict__ Wn0,
    const float* __restrict__ Ws1, const float* __restrict__ Wn1,
    int* __restrict__ cnt, u16* __restrict__ Bt0, u16* __restrict__ Bt1) {
  int t = blockIdx.x * 256 + threadIdx.x;
  if (t < E0_) { atomicAdd(&cnt[dst0[t]], 1); return; }
  t -= E0_;
  if (t < E1_) { atomicAdd(&cnt[N1_ + dst1[t]], 1); return; }
  t -= E1_;
  if (t < E2_) { atomicAdd(&cnt[N1_ + N2_ + dst2[t]], 1); return; }
  t -= E2_;
  if (t < 256 * 256) {  // Bt0: [n][k], KT=256
    int n = t & 255, k = t >> 8;
    float v = (k < IN_) ? Ws0[(size_t)k * 256 + n] : Wn0[(size_t)(k - IN_) * 256 + n];
    Bt0[(size_t)n * 256 + k] = f2b(v);
    return;
  }
  t -= 256 * 256;
  if (t < 256 * 512) {  // Bt1: [n][k], KT=512
    int n = t & 255, k = t >> 8;
    float v = (k < HID_) ? Ws1[(size_t)k * 256 + n] : Wn1[(size_t)(k - HID_) * 256 + n];
    Bt1[(size_t)n * 512 + k] = f2b(v);
  }
}

// ---------------- scan over NTOT counts ----------------
__global__ __launch_bounds__(256) void scan_local(const int* __restrict__ in,
                                                  int* __restrict__ out,
                                                  int* __restrict__ bsum, int n) {
  __shared__ int s[256];
  const int b = blockIdx.x, t = threadIdx.x;
  const int base = b * 2048 + t * 8;
  int v[8];
  int sum = 0;
#pragma unroll
  for (int i = 0; i < 8; i++) {
    int idx = base + i;
    int x = (idx < n) ? in[idx] : 0;
    v[i] = sum;
    sum += x;
  }
  s[t] = sum;
  __syncthreads();
  for (int off = 1; off < 256; off <<= 1) {
    int x = 0;
    if (t >= off) x = s[t - off];
    __syncthreads();
    if (t >= off) s[t] += x;
    __syncthreads();
  }
  const int texcl = s[t] - sum;
#pragma unroll
  for (int i = 0; i < 8; i++) {
    int idx = base + i;
    if (idx < n) out[idx] = texcl + v[i];
  }
  if (t == 255) bsum[b] = s[255];
}

__global__ __launch_bounds__(256) void scan_add(int* __restrict__ rptr,
                                                const int* __restrict__ bsum,
                                                int n, int E) {
  const int b = blockIdx.x, t = threadIdx.x;
  int add = 0;
  for (int i = 0; i < b; i++) add += bsum[i];
  const int base = b * 2048 + t * 8;
#pragma unroll
  for (int i = 0; i < 8; i++) {
    int idx = base + i;
    if (idx < n) rptr[idx] += add;
  }
  if (b == 0 && t == 0) rptr[n] = E;
}

// ---------------- combined fill: block-diagonal CSR ----------------
__global__ __launch_bounds__(256) void csr_fill_all(
    const int* __restrict__ src0, const int* __restrict__ dst0,
    const int* __restrict__ src1, const int* __restrict__ dst1,
    const int* __restrict__ src2, const int* __restrict__ dst2,
    const int* __restrict__ rptr, int* __restrict__ cursor,
    int* __restrict__ eids) {
  int e = blockIdx.x * 256 + threadIdx.x;
  int s, b;
  if (e < E0_) { s = src0[e]; b = dst0[e]; }
  else if (e < E0_ + E1_) { s = src1[e - E0_]; b = N1_ + dst1[e - E0_]; }
  else if (e < ETOT_) { s = src2[e - E0_ - E1_]; b = N1_ + N2_ + dst2[e - E0_ - E1_]; }
  else return;
  int pos = rptr[b] + atomicAdd(&cursor[b], 1);
  eids[pos] = s;
}

// ---------------- layer-0 aggregate: fp32 source, F=128, 16 edges in flight ----------------
__global__ __launch_bounds__(256) void agg0(const float* __restrict__ h,
                                            const int* __restrict__ eids,
                                            const int* __restrict__ rptr,
                                            u16* __restrict__ out, int M) {
  int wid = (blockIdx.x * 256 + threadIdx.x) >> 6;
  int lane = threadIdx.x & 63;
  if (wid >= M) return;
  const int beg = rptr[wid], end = rptr[wid + 1];
  const int half = lane >> 5;        // 0: even edges, 1: odd edges
  const int col = (lane & 31) * 4;   // fp32 col
  float a0 = 0.f, a1 = 0.f, a2 = 0.f, a3 = 0.f;
  for (int i = beg; i < end; i += 16) {
    int ids[8];
#pragma unroll
    for (int j = 0; j < 8; j++) {
      int idx = i + 2 * j + half;
      idx = idx < end ? idx : end - 1;
      ids[j] = eids[idx];
    }
    float4 v[8];
#pragma unroll
    for (int j = 0; j < 8; j++)
      v[j] = *reinterpret_cast<const float4*>(&h[(size_t)ids[j] * IN_ + col]);
#pragma unroll
    for (int j = 0; j < 8; j++) {
      if (i + 2 * j + half < end) {
        a0 += v[j].x; a1 += v[j].y; a2 += v[j].z; a3 += v[j].w;
      }
    }
  }
  a0 += __shfl_xor(a0, 32, 64);
  a1 += __shfl_xor(a1, 32, 64);
  a2 += __shfl_xor(a2, 32, 64);
  a3 += __shfl_xor(a3, 32, 64);
  if (half == 0) {
    float inv = 1.0f / fmaxf((float)(end - beg), 1.0f);
    u16x4 o;
    o[0] = f2b(a0 * inv); o[1] = f2b(a1 * inv);
    o[2] = f2b(a2 * inv); o[3] = f2b(a3 * inv);
    *reinterpret_cast<u16x4*>(&out[(size_t)wid * IN_ + col]) = o;
  }
}

// ---------------- layer-1 aggregate (bf16 source, F=256) ----------------
__global__ __launch_bounds__(256) void agg1(const u16* __restrict__ h,
                                            const int* __restrict__ eids,
                                            const int* __restrict__ rptr,
                                            u16* __restrict__ out, int M) {
  int wid = (blockIdx.x * 256 + threadIdx.x) >> 6;
  int lane = threadIdx.x & 63;
  if (wid >= M) return;
  const int beg = rptr[wid], end = rptr[wid + 1];
  const int half = lane >> 5;
  const int col = (lane & 31) * 8;
  float a[8];
#pragma unroll
  for (int j = 0; j < 8; j++) a[j] = 0.f;
  for (int i = beg; i < end; i += 16) {
    int ids[8];
#pragma unroll
    for (int j = 0; j < 8; j++) {
      int idx = i + 2 * j + half;
      idx = idx < end ? idx : end - 1;
      ids[j] = eids[idx];
    }
    u16x8 v[8];
#pragma unroll
    for (int j = 0; j < 8; j++)
      v[j] = *reinterpret_cast<const u16x8*>(&h[(size_t)ids[j] * HID_ + col]);
#pragma unroll
    for (int j = 0; j < 8; j++) {
      if (i + 2 * j + half < end) {
#pragma unroll
        for (int c = 0; c < 8; c++) a[c] += b2f(v[j][c]);
      }
    }
  }
#pragma unroll
  for (int c = 0; c < 8; c++) a[c] += __shfl_xor(a[c], 32, 64);
  if (half == 0) {
    float inv = 1.0f / fmaxf((float)(end - beg), 1.0f);
    u16x8 o;
#pragma unroll
    for (int c = 0; c < 8; c++) o[c] = f2b(a[c] * inv);
    *reinterpret_cast<u16x8*>(&out[(size_t)wid * HID_ + col]) = o;
  }
}

// ---------------- MFMA GEMM: out[Mx256] = relu([A0|A1] @ Bt^T + bias) ----------------
// BM=128, BN=256, BK=64; 512 threads = 8 waves (2m x 4n quadrants).
// A staged to LDS (swizzled); B read DIRECTLY from global Bt (L2-resident, 128-256KB).
template <int KSELF, bool A0F32>
__global__ __launch_bounds__(512) void sage_gemm_mfma(
    const void* __restrict__ A0v, const u16* __restrict__ A1,
    const u16* __restrict__ Bt, const float* __restrict__ bias,
    u16* __restrict__ outp, int M) {
  constexpr int KTOT = 2 * KSELF;
  __shared__ u16 As[128 * 64];   // [m][k], XOR-swizzled, 16 KB
  const int tid = threadIdx.x;
  const int lane = tid & 63;
  const int w = tid >> 6;
  const int wm = w >> 2;         // 0..1: m-quadrant
  const int wn = w & 3;          // 0..3: n-quadrant
  const int m0 = blockIdx.x * 128;

  f32x4 acc[4][4];
#pragma unroll
  for (int m = 0; m < 4; m++)
#pragma unroll
    for (int n = 0; n < 4; n++) acc[m][n] = f32x4{0.f, 0.f, 0.f, 0.f};

  for (int kt = 0; kt < KTOT; kt += 64) {
    // ---- stage A tile (128 rows x 64 k) ----
    if (A0F32 && kt < KSELF) {
      const float* A0 = (const float*)A0v;
#pragma unroll
      for (int i = 0; i < 4; i++) {
        int e = tid + i * 512;           // 0..2047 float4s
        int row = e >> 4;
        int c = (e & 15) * 4;
        int rowg = m0 + row; if (rowg >= M) rowg = M - 1;
        float4 v = *reinterpret_cast<const float4*>(&A0[(size_t)rowg * KSELF + kt + c]);
        u32 p0 = (u32)f2b(v.x) | ((u32)f2b(v.y) << 16);
        u32 p1 = (u32)f2b(v.z) | ((u32)f2b(v.w) << 16);
        int byt = ((row * 64 + c) * 2) ^ ((row & 7) << 4);
        u32* dp = reinterpret_cast<u32*>(reinterpret_cast<char*>(As) + byt);
        dp[0] = p0; dp[1] = p1;
      }
    } else {
      const u16* src; int ksrc;
      if (!A0F32 && kt < KSELF) { src = (const u16*)A0v; ksrc = kt; }
      else                      { src = A1;              ksrc = kt - KSELF; }
#pragma unroll
      for (int i = 0; i < 2; i++) {
        int e = tid + i * 512;           // 0..1023 u16x8s
        int row = e >> 3;
        int ch = e & 7;
        int rowg = m0 + row; if (rowg >= M) rowg = M - 1;
        u16x8 v = *reinterpret_cast<const u16x8*>(&src[(size_t)rowg * KSELF + ksrc + ch * 8]);
        int byt = ((row * 64 + ch * 8) * 2) ^ ((row & 7) << 4);
        *reinterpret_cast<u16x8*>(reinterpret_cast<char*>(As) + byt) = v;
      }
    }
    __syncthreads();
    // ---- compute: 2 k-slices x 16 MFMA; B straight from L2 ----
#pragma unroll
    for (int kk = 0; kk < 64; kk += 32) {
      const int ksl = kk + (lane >> 4) * 8;
      b16x8 a[4], b[4];
#pragma unroll
      for (int n = 0; n < 4; n++) {
        int nrow = wn * 64 + n * 16 + (lane & 15);
        b[n] = *reinterpret_cast<const b16x8*>(&Bt[(size_t)nrow * KTOT + kt + ksl]);
      }
#pragma unroll
      for (int m = 0; m < 4; m++) {
        int row = wm * 64 + m * 16 + (lane & 15);
        int byt = (row * 128 + ksl * 2) ^ ((row & 7) << 4);
        a[m] = *reinterpret_cast<const b16x8*>(reinterpret_cast<const char*>(As) + byt);
      }
#pragma unroll
      for (int m = 0; m < 4; m++)
#pragma unroll
        for (int n = 0; n < 4; n++)
          acc[m][n] = __builtin_amdgcn_mfma_f32_16x16x32_bf16(a[m], b[n], acc[m][n], 0, 0, 0);
    }
    __syncthreads();
  }
  // ---- epilogue ----
  float bv[4];
#pragma unroll
  for (int n = 0; n < 4; n++) bv[n] = bias[wn * 64 + n * 16 + (lane & 15)];
#pragma unroll
  for (int m = 0; m < 4; m++) {
    int rowb = m0 + wm * 64 + m * 16 + ((lane >> 4) << 2);
#pragma unroll
    for (int r = 0; r < 4; r++) {
      int row = rowb + r;
      if (row < M) {
#pragma unroll
        for (int n = 0; n < 4; n++) {
          float v = acc[m][n][r] + bv[n];
          v = fmaxf(v, 0.0f);
          outp[(size_t)row * 256 + wn * 64 + n * 16 + (lane & 15)] = f2b(v);
        }
      }
    }
  }
}

// ---------------- fused final layer: gather + GEMM (M=2048, K=512, N=47) ----------------
__global__ __launch_bounds__(64) void fused_out(
    const u16* __restrict__ h, const int* __restrict__ eids,
    const int* __restrict__ rptr, const float* __restrict__ Ws,
    const float* __restrict__ Wn, const float* __restrict__ bias,
    float* __restrict__ out) {
  __shared__ float As[512];
  const int row = blockIdx.x;
  const int t = threadIdx.x;
  u16x4 a = *reinterpret_cast<const u16x4*>(&h[(size_t)row * 256 + t * 4]);
#pragma unroll
  for (int j = 0; j < 4; j++) As[t * 4 + j] = b2f(a[j]);
  const int beg = rptr[row], end = rptr[row + 1];
  float s0 = 0.f, s1 = 0.f, s2 = 0.f, s3 = 0.f;
  for (int i = beg; i < end; i += 4) {
    int i1 = (i + 1 < end) ? i + 1 : i;
    int i2 = (i + 2 < end) ? i + 2 : i;
    int i3 = (i + 3 < end) ? i + 3 : i;
    int e0 = eids[i], e1 = eids[i1], e2 = eids[i2], e3 = eids[i3];
    u16x4 v0 = *reinterpret_cast<const u16x4*>(&h[(size_t)e0 * 256 + t * 4]);
    u16x4 v1 = *reinterpret_cast<const u16x4*>(&h[(size_t)e1 * 256 + t * 4]);
    u16x4 v2 = *reinterpret_cast<const u16x4*>(&h[(size_t)e2 * 256 + t * 4]);
    u16x4 v3 = *reinterpret_cast<const u16x4*>(&h[(size_t)e3 * 256 + t * 4]);
    s0 += b2f(v0[0]); s1 += b2f(v0[1]); s2 += b2f(v0[2]); s3 += b2f(v0[3]);
    if (i + 1 < end) { s0 += b2f(v1[0]); s1 += b2f(v1[1]); s2 += b2f(v1[2]); s3 += b2f(v1[3]); }
    if (i + 2 < end) { s0 += b2f(v2[0]); s1 += b2f(v2[1]); s2 += b2f(v2[2]); s3 += b2f(v2[3]); }
    if (i + 3 < end) { s0 += b2f(v3[0]); s1 += b2f(v3[1]); s2 += b2f(v3[2]); s3 += b2f(v3[3]); }
  }
  float inv = 1.0f / fmaxf((float)(end - beg), 1.0f);
  As[256 + t * 4 + 0] = s0 * inv;
  As[256 + t * 4 + 1] = s1 * inv;
  As[256 + t * 4 + 2] = s2 * inv;
  As[256 + t * 4 + 3] = s3 * inv;
  __syncthreads();
  if (t < OUT_) {
    float s = bias[t];
#pragma unroll 8
    for (int k = 0; k < 256; k++) s = fmaf(As[k], Ws[k * 47 + t], s);
#pragma unroll 8
    for (int k = 0; k < 256; k++) s = fmaf(As[256 + k], Wn[k * 47 + t], s);
    out[(size_t)row * 47 + t] = s;
  }
}

// ---------------- host driver ----------------
extern "C" void kernel_launch(void* const* d_in, const int* in_sizes, int n_in,
                              void* d_out, int out_size, void* d_ws, size_t ws_size,
                              hipStream_t stream) {
  const float* x      = (const float*)d_in[0];
  const int*   src0   = (const int*)d_in[1];
  const int*   dst0   = (const int*)d_in[2];
  const int*   src1   = (const int*)d_in[3];
  const int*   dst1   = (const int*)d_in[4];
  const int*   src2   = (const int*)d_in[5];
  const int*   dst2   = (const int*)d_in[6];
  const float* Wself0 = (const float*)d_in[7];
  const float* Wneigh0= (const float*)d_in[8];
  const float* b0     = (const float*)d_in[9];
  const float* Wself1 = (const float*)d_in[10];
  const float* Wneigh1= (const float*)d_in[11];
  const float* b1     = (const float*)d_in[12];
  const float* Wself2 = (const float*)d_in[13];
  const float* Wneigh2= (const float*)d_in[14];
  const float* b2     = (const float*)d_in[15];

  int* wsi   = (int*)d_ws;
  int* cnt   = wsi + OFF_CNT;
  int* cursor= wsi + OFF_CUR;
  int* rptr  = wsi + OFF_RPTR;
  int* bsum  = wsi + OFF_BSUM;
  int* eids  = wsi + OFF_EIDS;
  u16* Bt0   = (u16*)(wsi + OFF_BT0);
  u16* Bt1   = (u16*)(wsi + OFF_BT1);
  u16* HN0   = (u16*)(wsi + OFF_HN0);
  u16* H1    = (u16*)(wsi + OFF_H1);
  u16* HN1   = (u16*)(wsi + OFF_HN1);
  u16* H2    = (u16*)(wsi + OFF_H2);
  float* out = (float*)d_out;

  // one memset for counts + cursors
  hipMemsetAsync(cnt, 0, (size_t)(2 * NTOT_) * 4, stream);

  // combined hist (3 layers) + weight packs
  {
    int total = ETOT_ + 256 * 256 + 256 * 512;
    prep<<<(total + 255) / 256, 256, 0, stream>>>(
        dst0, dst1, dst2, Wself0, Wneigh0, Wself1, Wneigh1, cnt, Bt0, Bt1);
  }
  // combined scan + fill (block-diagonal CSR over all 3 layers)
  {
    const int nb = (NTOT_ + 2047) / 2048;  // 109
    scan_local<<<nb, 256, 0, stream>>>(cnt, rptr, bsum, NTOT_);
    scan_add<<<nb, 256, 0, stream>>>(rptr, bsum, NTOT_, ETOT_);
    csr_fill_all<<<(ETOT_ + 255) / 256, 256, 0, stream>>>(
        src0, dst0, src1, dst1, src2, dst2, rptr, cursor, eids);
  }

  // ---- layer 0 ----
  agg0<<<(N1_ + 3) / 4, 256, 0, stream>>>(x, eids, rptr, HN0, N1_);
  sage_gemm_mfma<IN_, true><<<(N1_ + 127) / 128, 512, 0, stream>>>(
      x, HN0, Bt0, b0, H1, N1_);

  // ---- layer 1 ----
  agg1<<<(N2_ + 3) / 4, 256, 0, stream>>>(H1, eids, rptr + N1_, HN1, N2_);
  sage_gemm_mfma<HID_, false><<<(N2_ + 127) / 128, 512, 0, stream>>>(
      H1, HN1, Bt1, b1, H2, N2_);

  // ---- layer 2 (fused gather + output GEMM) ----
  fused_out<<<N3_, 64, 0, stream>>>(H2, eids, rptr + N1_ + N2_, Wself2, Wneigh2, b2, out);
}